// Round 1
// baseline (336.587 us; speedup 1.0000x reference)
//
#include <hip/hip_runtime.h>

// DistributedSpectralConvNd: B=4, CI=CO=32, N=64^3, M=16^3 retained modes.
// Truncated-DFT pipeline: F3 (rfft x3, 16 modes) -> F2 (x2, 32 modes) ->
// F1 (x1, 32 modes) -> per-mode 32x32 complex channel mix (+1/64^3 norm) ->
// I1 -> I2 -> I3 (irfft). All fp32 vector.

#define TWOPI_64 0.0981747704246810387f  // 2*pi/64

__device__ __forceinline__ void init_tw(float* tc, float* ts, int t, int nthr) {
  for (int i = t; i < 64; i += nthr) {
    float s, c;
    sincosf(TWOPI_64 * (float)i, &s, &c);
    tc[i] = c; ts[i] = s;
  }
}

// ---------------- F3: real DFT along x3, keep k3 in [0,16) ----------------
// in : x [bci][x1][x2][x3]  (slab per block = 64x64 floats)
// out: A [bci][x1][x2][k3]  float2 (slab = 64*16)
__global__ __launch_bounds__(512) void k_f3(const float* __restrict__ x,
                                            float2* __restrict__ o) {
  __shared__ float xs[64 * 65];
  __shared__ float tc[64], ts[64];
  const int t = threadIdx.x;
  init_tw(tc, ts, t, 512);
  const float4* xg = (const float4*)(x + (size_t)blockIdx.x * 4096);
  for (int q = t; q < 1024; q += 512) {
    float4 v = xg[q];
    int x2 = q >> 4, x3 = (q & 15) << 2;
    float* p = &xs[x2 * 65 + x3];
    p[0] = v.x; p[1] = v.y; p[2] = v.z; p[3] = v.w;
  }
  __syncthreads();
  const int k3 = t & 15, x2 = t >> 4;  // x2 in [0,32), also handles x2+32
  float r0 = 0.f, i0 = 0.f, r1 = 0.f, i1 = 0.f;
#pragma unroll 8
  for (int x3 = 0; x3 < 64; ++x3) {
    int idx = (k3 * x3) & 63;
    float c = tc[idx], s = ts[idx];
    float a0 = xs[x2 * 65 + x3], a1 = xs[(x2 + 32) * 65 + x3];
    r0 = fmaf(a0, c, r0); i0 = fmaf(-a0, s, i0);
    r1 = fmaf(a1, c, r1); i1 = fmaf(-a1, s, i1);
  }
  float2* ob = o + (size_t)blockIdx.x * 1024;
  ob[x2 * 16 + k3] = make_float2(r0, i0);
  ob[(x2 + 32) * 16 + k3] = make_float2(r1, i1);
}

// ---------------- F2: complex DFT along x2, keep 32 modes ----------------
// in : A slab [x2][k3] (1024 float2); out: B [bci][x1][k2i][k3] (512 float2)
__global__ __launch_bounds__(512) void k_f2(const float2* __restrict__ in,
                                            float2* __restrict__ o) {
  __shared__ float2 xs[1024];
  __shared__ float tc[64], ts[64];
  const int t = threadIdx.x;
  init_tw(tc, ts, t, 512);
  const float4* ig = (const float4*)(in + (size_t)blockIdx.x * 1024);
  float4* xs4 = (float4*)xs;
  for (int q = t; q < 512; q += 512) xs4[q] = ig[q];
  __syncthreads();
  const int k3 = t & 15, k2i = t >> 4;
  const int k2 = k2i + ((k2i >= 16) ? 32 : 0);
  float re = 0.f, im = 0.f;
#pragma unroll 8
  for (int x2 = 0; x2 < 64; ++x2) {
    int idx = (k2 * x2) & 63;
    float c = tc[idx], s = ts[idx];
    float2 v = xs[x2 * 16 + k3];
    re = fmaf(v.x, c, re); re = fmaf(v.y, s, re);
    im = fmaf(v.y, c, im); im = fmaf(-v.x, s, im);
  }
  o[(size_t)blockIdx.x * 512 + t] = make_float2(re, im);
}

// ---------------- F1: complex DFT along x1, keep 32 modes ----------------
// grid: bci(128) x k2i(32). in B [bci][x1][k2i][k3] -> C [bci][k1i][k2i][k3]
__global__ __launch_bounds__(512) void k_f1(const float2* __restrict__ in,
                                            float2* __restrict__ o) {
  __shared__ float2 xs[1024];  // [x1][k3]
  __shared__ float tc[64], ts[64];
  const int t = threadIdx.x;
  init_tw(tc, ts, t, 512);
  const int bci = blockIdx.x >> 5, k2i = blockIdx.x & 31;
  for (int q = t; q < 1024; q += 512) {
    int x1 = q >> 4, k3 = q & 15;
    xs[q] = in[(((size_t)bci * 64 + x1) * 32 + k2i) * 16 + k3];
  }
  __syncthreads();
  const int k3 = t & 15, k1i = t >> 4;
  const int k1 = k1i + ((k1i >= 16) ? 32 : 0);
  float re = 0.f, im = 0.f;
#pragma unroll 8
  for (int x1 = 0; x1 < 64; ++x1) {
    int idx = (k1 * x1) & 63;
    float c = tc[idx], s = ts[idx];
    float2 v = xs[x1 * 16 + k3];
    re = fmaf(v.x, c, re); re = fmaf(v.y, s, re);
    im = fmaf(v.y, c, im); im = fmaf(-v.x, s, im);
  }
  o[(((size_t)bci * 32 + k1i) * 32 + k2i) * 16 + k3] = make_float2(re, im);
}

// ---------------- Mix: per-mode CIxCO complex matvec + 1/64^3 ----------------
// grid: k1i(32) x k2i(32). X [b*32+ci][k1i][k2i][k3] -> Y [b*32+co][k1i][k2i][k3]
__global__ __launch_bounds__(512) void k_mix(const float2* __restrict__ X,
                                             const float2* __restrict__ w0,
                                             const float2* __restrict__ w1,
                                             const float2* __restrict__ w2,
                                             const float2* __restrict__ w3,
                                             float2* __restrict__ Y) {
  __shared__ float2 xs[2048];  // [b*32+ci][k3]
  const int t = threadIdx.x;
  const int k1i = blockIdx.x >> 5, k2i = blockIdx.x & 31;
  const float2* w = (k1i < 16) ? ((k2i < 16) ? w0 : w1) : ((k2i < 16) ? w2 : w3);
  const int a = k1i & 15, bb = k2i & 15;
  for (int q = t; q < 2048; q += 512) {
    int bci = q >> 4, k3 = q & 15;
    xs[q] = X[((size_t)bci * 1024 + blockIdx.x) * 16 + k3];
  }
  __syncthreads();
  const int k3 = t & 15, co = t >> 4;
  float2 a0 = {0, 0}, a1 = {0, 0}, a2 = {0, 0}, a3 = {0, 0};
  const float2* wp = w + (size_t)co * 4096 + a * 256 + bb * 16 + k3;
#pragma unroll 4
  for (int ci = 0; ci < 32; ++ci) {
    float2 wv = wp[(size_t)ci * 131072];  // ci stride = 32*16*16*16 float2
    float2 x0 = xs[(0 * 32 + ci) * 16 + k3];
    float2 x1 = xs[(1 * 32 + ci) * 16 + k3];
    float2 x2 = xs[(2 * 32 + ci) * 16 + k3];
    float2 x3 = xs[(3 * 32 + ci) * 16 + k3];
    a0.x = fmaf(x0.x, wv.x, a0.x); a0.x = fmaf(-x0.y, wv.y, a0.x);
    a0.y = fmaf(x0.x, wv.y, a0.y); a0.y = fmaf(x0.y, wv.x, a0.y);
    a1.x = fmaf(x1.x, wv.x, a1.x); a1.x = fmaf(-x1.y, wv.y, a1.x);
    a1.y = fmaf(x1.x, wv.y, a1.y); a1.y = fmaf(x1.y, wv.x, a1.y);
    a2.x = fmaf(x2.x, wv.x, a2.x); a2.x = fmaf(-x2.y, wv.y, a2.x);
    a2.y = fmaf(x2.x, wv.y, a2.y); a2.y = fmaf(x2.y, wv.x, a2.y);
    a3.x = fmaf(x3.x, wv.x, a3.x); a3.x = fmaf(-x3.y, wv.y, a3.x);
    a3.y = fmaf(x3.x, wv.y, a3.y); a3.y = fmaf(x3.y, wv.x, a3.y);
  }
  const float nrm = 1.0f / 262144.0f;  // 1/64^3 folded here
  Y[((size_t)(0 * 32 + co) * 1024 + blockIdx.x) * 16 + k3] = make_float2(a0.x * nrm, a0.y * nrm);
  Y[((size_t)(1 * 32 + co) * 1024 + blockIdx.x) * 16 + k3] = make_float2(a1.x * nrm, a1.y * nrm);
  Y[((size_t)(2 * 32 + co) * 1024 + blockIdx.x) * 16 + k3] = make_float2(a2.x * nrm, a2.y * nrm);
  Y[((size_t)(3 * 32 + co) * 1024 + blockIdx.x) * 16 + k3] = make_float2(a3.x * nrm, a3.y * nrm);
}

// ---------------- I1: inverse DFT k1 -> x1 (64 outputs from 32 bins) ----------------
// grid: bco(128) x k2i(32). Y [bco][k1i][k2i][k3] -> Z1 [bco][x1][k2i][k3]
__global__ __launch_bounds__(512) void k_i1(const float2* __restrict__ Y,
                                            float2* __restrict__ o) {
  __shared__ float2 xs[512];  // [k1i][k3]
  __shared__ float tc[64], ts[64];
  const int t = threadIdx.x;
  init_tw(tc, ts, t, 512);
  const int bco = blockIdx.x >> 5, k2i = blockIdx.x & 31;
  for (int q = t; q < 512; q += 512) {
    int k1i = q >> 4, k3 = q & 15;
    xs[q] = Y[(((size_t)bco * 32 + k1i) * 32 + k2i) * 16 + k3];
  }
  __syncthreads();
  const int k3 = t & 15, x1 = t >> 4;  // x1 in [0,32), also x1+32
  float r0 = 0.f, i0 = 0.f, r1 = 0.f, i1 = 0.f;
#pragma unroll 8
  for (int k1i = 0; k1i < 32; ++k1i) {
    int k1 = k1i + ((k1i >= 16) ? 32 : 0);
    int idx = (k1 * x1) & 63;
    int idx2 = (idx + ((k1 & 1) << 5)) & 63;  // (k1*(x1+32)) & 63
    float c = tc[idx], s = ts[idx];
    float c2 = tc[idx2], s2 = ts[idx2];
    float2 v = xs[k1i * 16 + k3];
    r0 = fmaf(v.x, c, r0); r0 = fmaf(-v.y, s, r0);
    i0 = fmaf(v.y, c, i0); i0 = fmaf(v.x, s, i0);
    r1 = fmaf(v.x, c2, r1); r1 = fmaf(-v.y, s2, r1);
    i1 = fmaf(v.y, c2, i1); i1 = fmaf(v.x, s2, i1);
  }
  o[(((size_t)bco * 64 + x1) * 32 + k2i) * 16 + k3] = make_float2(r0, i0);
  o[(((size_t)bco * 64 + x1 + 32) * 32 + k2i) * 16 + k3] = make_float2(r1, i1);
}

// ---------------- I2: inverse DFT k2 -> x2 ----------------
// grid: bco*64+x1 (8192). Z1 slab [k2i][k3] (512 float2) -> Z2 slab [x2][k3] (1024)
__global__ __launch_bounds__(512) void k_i2(const float2* __restrict__ Z1,
                                            float2* __restrict__ o) {
  __shared__ float2 xs[512];
  __shared__ float tc[64], ts[64];
  const int t = threadIdx.x;
  init_tw(tc, ts, t, 512);
  const float4* ig = (const float4*)(Z1 + (size_t)blockIdx.x * 512);
  float4* xs4 = (float4*)xs;
  for (int q = t; q < 256; q += 512) xs4[q] = ig[q];
  if (t < 256) { }  // (first 256 threads did the load)
  __syncthreads();
  const int k3 = t & 15, x2 = t >> 4;  // x2 in [0,32), also x2+32
  float r0 = 0.f, i0 = 0.f, r1 = 0.f, i1 = 0.f;
#pragma unroll 8
  for (int k2i = 0; k2i < 32; ++k2i) {
    int k2 = k2i + ((k2i >= 16) ? 32 : 0);
    int idx = (k2 * x2) & 63;
    int idx2 = (idx + ((k2 & 1) << 5)) & 63;
    float c = tc[idx], s = ts[idx];
    float c2 = tc[idx2], s2 = ts[idx2];
    float2 v = xs[k2i * 16 + k3];
    r0 = fmaf(v.x, c, r0); r0 = fmaf(-v.y, s, r0);
    i0 = fmaf(v.y, c, i0); i0 = fmaf(v.x, s, i0);
    r1 = fmaf(v.x, c2, r1); r1 = fmaf(-v.y, s2, r1);
    i1 = fmaf(v.y, c2, i1); i1 = fmaf(v.x, s2, i1);
  }
  float2* ob = o + (size_t)blockIdx.x * 1024;
  ob[x2 * 16 + k3] = make_float2(r0, i0);
  ob[(x2 + 32) * 16 + k3] = make_float2(r1, i1);
}

// ---------------- I3: irfft k3 -> x3 (real output) ----------------
// grid: bco*64+x1 (8192). Z2 slab [x2][k3] (1024 float2) -> out slab [x2][x3] (4096 f)
__global__ __launch_bounds__(512) void k_i3(const float2* __restrict__ Z2,
                                            float* __restrict__ out) {
  __shared__ float2 xs[1024];
  __shared__ float tc[64], ts[64];
  const int t = threadIdx.x;
  init_tw(tc, ts, t, 512);
  for (int q = t; q < 1024; q += 512) {
    float2 v = Z2[(size_t)blockIdx.x * 1024 + q];
    if (q & 15) { v.x *= 2.f; v.y *= 2.f; }  // Hermitian double-count, k>0
    xs[q] = v;
  }
  __syncthreads();
  const int x3 = t & 63;
  const int x2g = t >> 6;  // wave id: x2 uniform per wave -> LDS broadcast
  for (int r = 0; r < 8; ++r) {
    int x2 = x2g + r * 8;
    float val = 0.f;
#pragma unroll
    for (int k = 0; k < 16; ++k) {
      int idx = (k * x3) & 63;
      float2 v = xs[x2 * 16 + k];
      val = fmaf(v.x, tc[idx], val);
      val = fmaf(-v.y, ts[idx], val);
    }
    out[(size_t)blockIdx.x * 4096 + x2 * 64 + x3] = val;
  }
}

extern "C" void kernel_launch(void* const* d_in, const int* in_sizes, int n_in,
                              void* d_out, int out_size, void* d_ws, size_t ws_size,
                              hipStream_t stream) {
  (void)in_sizes; (void)n_in; (void)out_size; (void)ws_size;
  const float* x = (const float*)d_in[0];
  const float2* w0 = (const float2*)d_in[1];
  const float2* w1 = (const float2*)d_in[2];
  const float2* w2 = (const float2*)d_in[3];
  const float2* w3 = (const float2*)d_in[4];
  float* out = (float*)d_out;
  char* ws = (char*)d_ws;

  // Workspace plan (needs 100,663,296 B):
  //  A = ws[0 : 67108864)          F3 out, later I2 out
  //  B = ws[67108864 : 100663296)  F2 out, later I1 out
  //  C = A[0 : 16777216)           F1 out (A dead after F2)
  //  D = A[16777216 : 33554432)    mix out (disjoint from C)
  float2* bufA = (float2*)ws;
  float2* bufB = (float2*)(ws + 67108864);
  float2* bufC = (float2*)ws;
  float2* bufD = (float2*)(ws + 16777216);

  k_f3<<<8192, 512, 0, stream>>>(x, bufA);
  k_f2<<<8192, 512, 0, stream>>>(bufA, bufB);
  k_f1<<<4096, 512, 0, stream>>>(bufB, bufC);
  k_mix<<<1024, 512, 0, stream>>>(bufC, w0, w1, w2, w3, bufD);
  k_i1<<<4096, 512, 0, stream>>>(bufD, bufB);
  k_i2<<<8192, 512, 0, stream>>>(bufB, bufA);
  k_i3<<<8192, 512, 0, stream>>>(bufA, out);
}

// Round 2
// 224.592 us; speedup vs baseline: 1.4987x; 1.4987x over previous
//
#include <hip/hip_runtime.h>

// FNO spectral conv: B=4, CI=CO=32, N=64^3, M=16^3 modes, 4 corners.
// 5-kernel truncated-DFT pipeline with fused (F3+F2) and (I2+I3):
//   k_f23: x -> B1[bci][x1][k2i][k3]        (real rfft x3 -> 16, DFT x2 -> 32)
//   k_f1 : B1 -> C[bci][k1i][k2i][k3]       (DFT x1 -> 32, conj-pair trick)
//   k_mix: C -> D (per-mode 32x32 complex channel mix, + 1/64^3)
//   k_i1 : D -> B2[bco][x1][k2i][k3]        (inverse x1, E/O parity trick)
//   k_i23: B2 -> out                        (inverse x2 + irfft x3, E/O)
// k2i/k1i convention: i in [0,16) -> mode i ; i in [16,32) -> mode i+32.

#define TWOPI_64 0.0981747704246810387f  // 2*pi/64

__device__ __forceinline__ void init_tw2(float2* tw, int t) {
  if (t < 64) {
    float s, c;
    sincosf(TWOPI_64 * (float)t, &s, &c);
    tw[t] = make_float2(c, s);
  }
}

// ---------------- F23: per (bci,x1) plane ----------------
__global__ __launch_bounds__(512) void k_f23(const float* __restrict__ x,
                                             float2* __restrict__ o) {
  __shared__ float xs[64 * 65];     // [x2][x3] padded
  __shared__ float2 Xc[16 * 65];    // [k3][x2] padded
  __shared__ float4 red[512];       // PQRS partials
  __shared__ float2 redAB[32];      // k=0 partials
  __shared__ float2 tw[64];
  const int t = threadIdx.x;
  init_tw2(tw, t);
  const float4* xg = (const float4*)(x + (size_t)blockIdx.x * 4096);
  for (int q = t; q < 1024; q += 512) {
    float4 v = xg[q];
    int x2 = q >> 4, x3 = (q & 15) << 2;
    float* p = &xs[x2 * 65 + x3];
    p[0] = v.x; p[1] = v.y; p[2] = v.z; p[3] = v.w;
  }
  __syncthreads();
  // stage 1: real DFT x3 -> k3 in [0,16). thread: k3 = t&15, rows x2,x2+32.
  {
    const int k3 = t & 15, x2 = t >> 4;
    float r0 = 0.f, i0 = 0.f, r1 = 0.f, i1 = 0.f;
    int idx = 0;
    const float* row0 = &xs[x2 * 65];
    const float* row1 = &xs[(x2 + 32) * 65];
#pragma unroll 8
    for (int x3 = 0; x3 < 64; ++x3) {
      float2 w = tw[idx];
      idx = (idx + k3) & 63;
      float a0 = row0[x3], a1 = row1[x3];
      r0 = fmaf(a0, w.x, r0); i0 = fmaf(-a0, w.y, i0);
      r1 = fmaf(a1, w.x, r1); i1 = fmaf(-a1, w.y, i1);
    }
    Xc[k3 * 65 + x2] = make_float2(r0, i0);
    Xc[k3 * 65 + x2 + 32] = make_float2(r1, i1);
  }
  __syncthreads();
  // stage 2: complex DFT x2 -> 32 modes via conj pairs (s, 64-s), slot0=(0,48).
  {
    const int k3 = t & 15, slot = (t >> 4) & 15, h = t >> 8;
    const bool isz = (slot == 0);
    const int kk = isz ? 48 : slot;
    float P = 0, Q = 0, R = 0, S = 0, A = 0, Bm = 0;
    int idx = (kk * 32 * h) & 63;
#pragma unroll 8
    for (int j = 0; j < 32; ++j) {
      int x2 = 32 * h + j;
      float2 v = Xc[k3 * 65 + x2];
      float2 w = tw[idx];
      idx = (idx + kk) & 63;
      P = fmaf(v.x, w.x, P); Q = fmaf(v.y, w.y, Q);
      R = fmaf(v.y, w.x, R); S = fmaf(v.x, w.y, S);
      if (isz) { A += v.x; Bm += v.y; }
    }
    red[t] = make_float4(P, Q, R, S);
    if (isz) redAB[h * 16 + k3] = make_float2(A, Bm);
  }
  __syncthreads();
  if (t < 256) {
    const int k3 = t & 15, slot = t >> 4;
    float4 p0 = red[t], p1 = red[t + 256];
    float P = p0.x + p1.x, Q = p0.y + p1.y, R = p0.z + p1.z, S = p0.w + p1.w;
    float2 oa = make_float2(P + Q, R - S);   // forward: re=P+Q, im=R-S
    float2 ob;
    int ka, kb;
    if (slot == 0) {
      ka = 16; kb = 0;  // PQRS was k=48 -> k2i=16 ; A,B is k=0 -> k2i=0
      ob = make_float2(redAB[k3].x + redAB[16 + k3].x,
                       redAB[k3].y + redAB[16 + k3].y);
    } else {
      ka = slot; kb = 32 - slot;             // k=64-slot -> k2i=32-slot
      ob = make_float2(P - Q, R + S);        // conj twiddle combine
    }
    float2* og = o + (size_t)blockIdx.x * 512;
    og[ka * 16 + k3] = oa;
    og[kb * 16 + k3] = ob;
  }
}

// ---------------- F1: per (bci,k2i) ----------------
__global__ __launch_bounds__(512) void k_f1(const float2* __restrict__ in,
                                            float2* __restrict__ o) {
  __shared__ float2 xs[64 * 16];    // [x1][k3]
  __shared__ float4 red[512];
  __shared__ float2 redAB[32];
  __shared__ float2 tw[64];
  const int t = threadIdx.x;
  init_tw2(tw, t);
  const int bci = blockIdx.x >> 5, k2i = blockIdx.x & 31;
  for (int q = t; q < 1024; q += 512) {
    int x1 = q >> 4, k3 = q & 15;
    xs[q] = in[(((size_t)bci * 64 + x1) * 32 + k2i) * 16 + k3];
  }
  __syncthreads();
  {
    const int k3 = t & 15, slot = (t >> 4) & 15, h = t >> 8;
    const bool isz = (slot == 0);
    const int kk = isz ? 48 : slot;
    float P = 0, Q = 0, R = 0, S = 0, A = 0, Bm = 0;
    int idx = (kk * 32 * h) & 63;
#pragma unroll 8
    for (int j = 0; j < 32; ++j) {
      int x1 = 32 * h + j;
      float2 v = xs[x1 * 16 + k3];
      float2 w = tw[idx];
      idx = (idx + kk) & 63;
      P = fmaf(v.x, w.x, P); Q = fmaf(v.y, w.y, Q);
      R = fmaf(v.y, w.x, R); S = fmaf(v.x, w.y, S);
      if (isz) { A += v.x; Bm += v.y; }
    }
    red[t] = make_float4(P, Q, R, S);
    if (isz) redAB[h * 16 + k3] = make_float2(A, Bm);
  }
  __syncthreads();
  if (t < 256) {
    const int k3 = t & 15, slot = t >> 4;
    float4 p0 = red[t], p1 = red[t + 256];
    float P = p0.x + p1.x, Q = p0.y + p1.y, R = p0.z + p1.z, S = p0.w + p1.w;
    float2 oa = make_float2(P + Q, R - S);
    float2 ob;
    int ka, kb;
    if (slot == 0) {
      ka = 16; kb = 0;
      ob = make_float2(redAB[k3].x + redAB[16 + k3].x,
                       redAB[k3].y + redAB[16 + k3].y);
    } else {
      ka = slot; kb = 32 - slot;
      ob = make_float2(P - Q, R + S);
    }
    o[(((size_t)bci * 32 + ka) * 32 + k2i) * 16 + k3] = oa;
    o[(((size_t)bci * 32 + kb) * 32 + k2i) * 16 + k3] = ob;
  }
}

// ---------------- Mix: per-mode CIxCO complex matvec + 1/64^3 ----------------
__global__ __launch_bounds__(512) void k_mix(const float2* __restrict__ X,
                                             const float2* __restrict__ w0,
                                             const float2* __restrict__ w1,
                                             const float2* __restrict__ w2,
                                             const float2* __restrict__ w3,
                                             float2* __restrict__ Y) {
  __shared__ float2 xs[2048];  // [b*32+ci][k3]
  const int t = threadIdx.x;
  const int k1i = blockIdx.x >> 5, k2i = blockIdx.x & 31;
  const float2* w = (k1i < 16) ? ((k2i < 16) ? w0 : w1) : ((k2i < 16) ? w2 : w3);
  const int a = k1i & 15, bb = k2i & 15;
  for (int q = t; q < 2048; q += 512) {
    int bci = q >> 4, k3 = q & 15;
    xs[q] = X[((size_t)bci * 1024 + blockIdx.x) * 16 + k3];
  }
  __syncthreads();
  const int k3 = t & 15, co = t >> 4;
  float2 a0 = {0, 0}, a1 = {0, 0}, a2 = {0, 0}, a3 = {0, 0};
  const float2* wp = w + (size_t)co * 4096 + a * 256 + bb * 16 + k3;
#pragma unroll 4
  for (int ci = 0; ci < 32; ++ci) {
    float2 wv = wp[(size_t)ci * 131072];
    float2 x0 = xs[(0 * 32 + ci) * 16 + k3];
    float2 x1 = xs[(1 * 32 + ci) * 16 + k3];
    float2 x2 = xs[(2 * 32 + ci) * 16 + k3];
    float2 x3 = xs[(3 * 32 + ci) * 16 + k3];
    a0.x = fmaf(x0.x, wv.x, a0.x); a0.x = fmaf(-x0.y, wv.y, a0.x);
    a0.y = fmaf(x0.x, wv.y, a0.y); a0.y = fmaf(x0.y, wv.x, a0.y);
    a1.x = fmaf(x1.x, wv.x, a1.x); a1.x = fmaf(-x1.y, wv.y, a1.x);
    a1.y = fmaf(x1.x, wv.y, a1.y); a1.y = fmaf(x1.y, wv.x, a1.y);
    a2.x = fmaf(x2.x, wv.x, a2.x); a2.x = fmaf(-x2.y, wv.y, a2.x);
    a2.y = fmaf(x2.x, wv.y, a2.y); a2.y = fmaf(x2.y, wv.x, a2.y);
    a3.x = fmaf(x3.x, wv.x, a3.x); a3.x = fmaf(-x3.y, wv.y, a3.x);
    a3.y = fmaf(x3.x, wv.y, a3.y); a3.y = fmaf(x3.y, wv.x, a3.y);
  }
  const float nrm = 1.0f / 262144.0f;
  Y[((size_t)(0 * 32 + co) * 1024 + blockIdx.x) * 16 + k3] = make_float2(a0.x * nrm, a0.y * nrm);
  Y[((size_t)(1 * 32 + co) * 1024 + blockIdx.x) * 16 + k3] = make_float2(a1.x * nrm, a1.y * nrm);
  Y[((size_t)(2 * 32 + co) * 1024 + blockIdx.x) * 16 + k3] = make_float2(a2.x * nrm, a2.y * nrm);
  Y[((size_t)(3 * 32 + co) * 1024 + blockIdx.x) * 16 + k3] = make_float2(a3.x * nrm, a3.y * nrm);
}

// ---------------- I1: inverse x1, E/O parity trick ----------------
__global__ __launch_bounds__(512) void k_i1(const float2* __restrict__ Y,
                                            float2* __restrict__ o) {
  __shared__ float2 xs[32 * 16];  // [k1i][k3]
  __shared__ float2 tw[64];
  const int t = threadIdx.x;
  init_tw2(tw, t);
  const int bco = blockIdx.x >> 5, k2i = blockIdx.x & 31;
  xs[t] = Y[(((size_t)bco * 32 + (t >> 4)) * 32 + k2i) * 16 + (t & 15)];
  __syncthreads();
  const int k3 = t & 15, x1 = t >> 4;  // x1 in [0,32), pairs with x1+32
  float Er = 0, Ei = 0, Or = 0, Oi = 0;
#pragma unroll 4
  for (int m = 0; m < 16; ++m) {
    int e = 2 * m, od = 2 * m + 1;
    int ke = e + ((e >= 16) ? 32 : 0);
    int ko = od + ((od >= 16) ? 32 : 0);
    float2 v = xs[e * 16 + k3];
    float2 w = tw[(ke * x1) & 63];
    Er = fmaf(v.x, w.x, Er); Er = fmaf(-v.y, w.y, Er);
    Ei = fmaf(v.y, w.x, Ei); Ei = fmaf(v.x, w.y, Ei);
    float2 v2 = xs[od * 16 + k3];
    float2 w2 = tw[(ko * x1) & 63];
    Or = fmaf(v2.x, w2.x, Or); Or = fmaf(-v2.y, w2.y, Or);
    Oi = fmaf(v2.y, w2.x, Oi); Oi = fmaf(v2.x, w2.y, Oi);
  }
  o[(((size_t)bco * 64 + x1) * 32 + k2i) * 16 + k3] = make_float2(Er + Or, Ei + Oi);
  o[(((size_t)bco * 64 + x1 + 32) * 32 + k2i) * 16 + k3] = make_float2(Er - Or, Ei - Oi);
}

// ---------------- I23: per (bco,x1): inverse x2 then irfft x3 ----------------
__global__ __launch_bounds__(512) void k_i23(const float2* __restrict__ Z1,
                                             float* __restrict__ out) {
  __shared__ float2 zs[32 * 16];  // [k2i][k3]
  __shared__ float2 Zc[64 * 16];  // [x2][k3] (Hermitian 2x folded in)
  __shared__ float2 tw[64];
  const int t = threadIdx.x;
  init_tw2(tw, t);
  if (t < 256) {
    float4* zs4 = (float4*)zs;
    zs4[t] = ((const float4*)(Z1 + (size_t)blockIdx.x * 512))[t];
  }
  __syncthreads();
  // stage A: inverse DFT k2 -> x2 with E/O split
  {
    const int k3 = t & 15, x2 = t >> 4;  // x2 in [0,32), pairs with x2+32
    float Er = 0, Ei = 0, Or = 0, Oi = 0;
#pragma unroll 4
    for (int m = 0; m < 16; ++m) {
      int e = 2 * m, od = 2 * m + 1;
      int ke = e + ((e >= 16) ? 32 : 0);
      int ko = od + ((od >= 16) ? 32 : 0);
      float2 v = zs[e * 16 + k3];
      float2 w = tw[(ke * x2) & 63];
      Er = fmaf(v.x, w.x, Er); Er = fmaf(-v.y, w.y, Er);
      Ei = fmaf(v.y, w.x, Ei); Ei = fmaf(v.x, w.y, Ei);
      float2 v2 = zs[od * 16 + k3];
      float2 w2 = tw[(ko * x2) & 63];
      Or = fmaf(v2.x, w2.x, Or); Or = fmaf(-v2.y, w2.y, Or);
      Oi = fmaf(v2.y, w2.x, Oi); Oi = fmaf(v2.x, w2.y, Oi);
    }
    float sc = (k3 == 0) ? 1.f : 2.f;  // Hermitian double-count for k3>0
    Zc[x2 * 16 + k3] = make_float2(sc * (Er + Or), sc * (Ei + Oi));
    Zc[(x2 + 32) * 16 + k3] = make_float2(sc * (Er - Or), sc * (Ei - Oi));
  }
  __syncthreads();
  // stage B: irfft k3 -> x3 (real), E/O parity for (x3, x3+32)
  {
    const int x3 = t & 31, x2g = t >> 5;
    float2 wk[16];
#pragma unroll
    for (int k = 0; k < 16; ++k) wk[k] = tw[(k * x3) & 63];
    float* ob = out + (size_t)blockIdx.x * 4096;
#pragma unroll
    for (int r = 0; r < 4; ++r) {
      int x2 = x2g + 16 * r;
      const float4* Zp = (const float4*)&Zc[x2 * 16];
      float Er = 0, Or = 0;
#pragma unroll
      for (int j = 0; j < 8; ++j) {
        float4 z = Zp[j];                    // complex 2j and 2j+1
        float2 we = wk[2 * j], wo = wk[2 * j + 1];
        Er = fmaf(z.x, we.x, Er); Er = fmaf(-z.y, we.y, Er);
        Or = fmaf(z.z, wo.x, Or); Or = fmaf(-z.w, wo.y, Or);
      }
      ob[x2 * 64 + x3] = Er + Or;
      ob[x2 * 64 + x3 + 32] = Er - Or;
    }
  }
}

extern "C" void kernel_launch(void* const* d_in, const int* in_sizes, int n_in,
                              void* d_out, int out_size, void* d_ws, size_t ws_size,
                              hipStream_t stream) {
  (void)in_sizes; (void)n_in; (void)out_size; (void)ws_size;
  const float* x = (const float*)d_in[0];
  const float2* w0 = (const float2*)d_in[1];
  const float2* w1 = (const float2*)d_in[2];
  const float2* w2 = (const float2*)d_in[3];
  const float2* w3 = (const float2*)d_in[4];
  float* out = (float*)d_out;
  char* ws = (char*)d_ws;

  // Workspace (67,108,864 B total):
  //  B1 = ws[0 : 33.5MB)   f23 out; dead after f1 -> reused as B2 (i1 out)
  //  C  = ws[33.5 : 50.3MB) f1 out
  //  D  = ws[50.3 : 67.1MB) mix out
  float2* B1 = (float2*)ws;
  float2* C  = (float2*)(ws + 33554432);
  float2* D  = (float2*)(ws + 50331648);
  float2* B2 = B1;

  k_f23<<<8192, 512, 0, stream>>>(x, B1);
  k_f1 <<<4096, 512, 0, stream>>>(B1, C);
  k_mix<<<1024, 512, 0, stream>>>(C, w0, w1, w2, w3, D);
  k_i1 <<<4096, 512, 0, stream>>>(D, B2);
  k_i23<<<8192, 512, 0, stream>>>(B2, out);
}

// Round 3
// 220.164 us; speedup vs baseline: 1.5288x; 1.0201x over previous
//
#include <hip/hip_runtime.h>

// FNO spectral conv: B=4, CI=CO=32, N=64^3, M=16^3 modes, 4 corners.
// 5-kernel truncated-DFT pipeline, register-tiled LDS compute:
//   k_f23: x -> B1[bci*64+x1][k2i][k3]   (rfft x3 -> 16 modes, DFT x2 -> 32)
//   k_f1 : B1 -> C[bci][k1i][k2i][k3]    (DFT x1 -> 32, conj-pair PQRS)
//   k_mix: C -> D                        (per-mode 32x32 cplx channel mix)
//   k_i1 : D -> B2[bco][x1][k2i][k3]     (inverse x1, even/odd parity)
//   k_i23: B2 -> out                     (inverse x2 + irfft x3)
// mode index convention: i in [0,16) -> mode i ; [16,32) -> mode i+32.

#define TWOPI_64 0.0981747704246810387f  // 2*pi/64

__device__ __forceinline__ void init_tw2(float2* tw, int t) {
  if (t < 64) {
    float s, c;
    sincosf(TWOPI_64 * (float)t, &s, &c);
    tw[t] = make_float2(c, s);
  }
}

// ============================ F23 ============================
// per (bci,x1) plane. 512 thr.
__global__ __launch_bounds__(512) void k_f23(const float* __restrict__ x,
                                             float2* __restrict__ o) {
  __shared__ float4 xs4[64 * 17];   // [x2][chunk] pad-17 (quad = (x2+c)&7)
  __shared__ float2 twT[64 * 16];   // [x3][k3] transposed twiddle
  __shared__ float2 Xc[64 * 18];    // [x2][k3] pad-18
  __shared__ float4 red[2][512];
  __shared__ float4 redAB[32];
  __shared__ float2 tw[64];
  const int t = threadIdx.x;
  init_tw2(tw, t);
  for (int q = t; q < 1024; q += 512) {
    int x3 = q >> 4, k3 = q & 15;
    float s, c;
    sincosf(TWOPI_64 * (float)((k3 * x3) & 63), &s, &c);
    twT[q] = make_float2(c, s);
  }
  const float4* xg = (const float4*)(x + (size_t)blockIdx.x * 4096);
  for (int q = t; q < 1024; q += 512) {
    int x2 = q >> 4, c = q & 15;
    xs4[x2 * 17 + c] = xg[q];
  }
  __syncthreads();
  // ---- stage 1: real DFT x3 -> k3 in [0,16) ----
  // thread: k3 = t&15, u = (t>>4)&15, h = t>>8. rows u+16j, x3 in [32h,32h+32).
  {
    const int k3 = t & 15, u = (t >> 4) & 15, h = t >> 8;
    float2 a0 = {0,0}, a1 = {0,0}, a2 = {0,0}, a3 = {0,0};
#pragma unroll
    for (int cl = 0; cl < 8; ++cl) {
      int c = 8 * h + cl;
      float4 d0 = xs4[(u)*17 + c];
      float4 d1 = xs4[(u + 16)*17 + c];
      float4 d2 = xs4[(u + 32)*17 + c];
      float4 d3 = xs4[(u + 48)*17 + c];
      const float2* wr = &twT[(4 * c) * 16 + k3];
      float2 w0 = wr[0], w1 = wr[16], w2 = wr[32], w3 = wr[48];
      a0.x = fmaf(d0.x, w0.x, a0.x); a0.y = fmaf(-d0.x, w0.y, a0.y);
      a0.x = fmaf(d0.y, w1.x, a0.x); a0.y = fmaf(-d0.y, w1.y, a0.y);
      a0.x = fmaf(d0.z, w2.x, a0.x); a0.y = fmaf(-d0.z, w2.y, a0.y);
      a0.x = fmaf(d0.w, w3.x, a0.x); a0.y = fmaf(-d0.w, w3.y, a0.y);
      a1.x = fmaf(d1.x, w0.x, a1.x); a1.y = fmaf(-d1.x, w0.y, a1.y);
      a1.x = fmaf(d1.y, w1.x, a1.x); a1.y = fmaf(-d1.y, w1.y, a1.y);
      a1.x = fmaf(d1.z, w2.x, a1.x); a1.y = fmaf(-d1.z, w2.y, a1.y);
      a1.x = fmaf(d1.w, w3.x, a1.x); a1.y = fmaf(-d1.w, w3.y, a1.y);
      a2.x = fmaf(d2.x, w0.x, a2.x); a2.y = fmaf(-d2.x, w0.y, a2.y);
      a2.x = fmaf(d2.y, w1.x, a2.x); a2.y = fmaf(-d2.y, w1.y, a2.y);
      a2.x = fmaf(d2.z, w2.x, a2.x); a2.y = fmaf(-d2.z, w2.y, a2.y);
      a2.x = fmaf(d2.w, w3.x, a2.x); a2.y = fmaf(-d2.w, w3.y, a2.y);
      a3.x = fmaf(d3.x, w0.x, a3.x); a3.y = fmaf(-d3.x, w0.y, a3.y);
      a3.x = fmaf(d3.y, w1.x, a3.x); a3.y = fmaf(-d3.y, w1.y, a3.y);
      a3.x = fmaf(d3.z, w2.x, a3.x); a3.y = fmaf(-d3.z, w2.y, a3.y);
      a3.x = fmaf(d3.w, w3.x, a3.x); a3.y = fmaf(-d3.w, w3.y, a3.y);
    }
    red[0][t] = make_float4(a0.x, a0.y, a1.x, a1.y);
    red[1][t] = make_float4(a2.x, a2.y, a3.x, a3.y);
  }
  __syncthreads();
  if (t < 256) {  // combine h halves -> Xc
    const int k3 = t & 15, u = t >> 4;
    float4 p0 = red[0][t], p1 = red[0][t + 256];
    float4 q0 = red[1][t], q1 = red[1][t + 256];
    Xc[(u)*18 + k3]      = make_float2(p0.x + p1.x, p0.y + p1.y);
    Xc[(u + 16)*18 + k3] = make_float2(p0.z + p1.z, p0.w + p1.w);
    Xc[(u + 32)*18 + k3] = make_float2(q0.x + q1.x, q0.y + q1.y);
    Xc[(u + 48)*18 + k3] = make_float2(q0.z + q1.z, q0.w + q1.w);
  }
  __syncthreads();
  // ---- stage 2: complex DFT x2 -> 32 modes, conj pairs, k3-paired ----
  // thread: k3p = t&7, slot = (t>>3)&15, h = t>>7 (K quarter).
  {
    const int k3p = t & 7, slot = (t >> 3) & 15, h = t >> 7;
    const bool isz = (slot == 0);
    const int kk = isz ? 48 : slot;
    float Pa=0,Qa=0,Ra=0,Sa=0, Pb=0,Qb=0,Rb=0,Sb=0, Aa=0,Ba=0,Ab=0,Bb=0;
    int idx = (kk * 16 * h) & 63;
#pragma unroll
    for (int i = 0; i < 16; ++i) {
      int x2 = 16 * h + i;
      float4 v = *(const float4*)&Xc[x2 * 18 + 2 * k3p];
      float2 w = tw[idx]; idx = (idx + kk) & 63;
      Pa = fmaf(v.x, w.x, Pa); Qa = fmaf(v.y, w.y, Qa);
      Ra = fmaf(v.y, w.x, Ra); Sa = fmaf(v.x, w.y, Sa);
      Pb = fmaf(v.z, w.x, Pb); Qb = fmaf(v.w, w.y, Qb);
      Rb = fmaf(v.w, w.x, Rb); Sb = fmaf(v.z, w.y, Sb);
      if (isz) { Aa += v.x; Ba += v.y; Ab += v.z; Bb += v.w; }
    }
    red[0][k3p + 8 * slot + 128 * h] = make_float4(Pa, Qa, Ra, Sa);
    red[1][k3p + 8 * slot + 128 * h] = make_float4(Pb, Qb, Rb, Sb);
    if (isz) redAB[8 * h + k3p] = make_float4(Aa, Ba, Ab, Bb);
  }
  __syncthreads();
  if (t < 256) {
    const int slot = t >> 4, k3 = t & 15, k3p = k3 >> 1, half = k3 & 1;
    int b = k3p + 8 * slot;
    float4 s0 = red[half][b], s1 = red[half][b + 128];
    float4 s2 = red[half][b + 256], s3 = red[half][b + 384];
    float P = s0.x + s1.x + s2.x + s3.x, Q = s0.y + s1.y + s2.y + s3.y;
    float R = s0.z + s1.z + s2.z + s3.z, S = s0.w + s1.w + s2.w + s3.w;
    float2 oa = make_float2(P + Q, R - S);
    float2 ob; int ka, kb;
    if (slot == 0) {
      ka = 16; kb = 0;  // PQRS was mode 48 ; AB is mode 0
      const float2* ab = (const float2*)redAB;
      float2 z0 = ab[(0 * 8 + k3p) * 2 + half], z1 = ab[(1 * 8 + k3p) * 2 + half];
      float2 z2 = ab[(2 * 8 + k3p) * 2 + half], z3 = ab[(3 * 8 + k3p) * 2 + half];
      ob = make_float2(z0.x + z1.x + z2.x + z3.x, z0.y + z1.y + z2.y + z3.y);
    } else {
      ka = slot; kb = 32 - slot;
      ob = make_float2(P - Q, R + S);
    }
    float2* og = o + (size_t)blockIdx.x * 512;
    og[ka * 16 + k3] = oa;
    og[kb * 16 + k3] = ob;
  }
}

// ============================ F1 ============================
// per (bci,k2i). 512 thr. Same PQRS structure as f23 stage 2.
__global__ __launch_bounds__(512) void k_f1(const float2* __restrict__ in,
                                            float2* __restrict__ o) {
  __shared__ float2 xsf[64 * 18];
  __shared__ float4 red[2][512];
  __shared__ float4 redAB[32];
  __shared__ float2 tw[64];
  const int t = threadIdx.x;
  init_tw2(tw, t);
  const int bci = blockIdx.x >> 5, k2i = blockIdx.x & 31;
  {
    int x1 = t >> 3, k3p = t & 7;
    float4 v = ((const float4*)in)[((size_t)(bci * 64 + x1) * 32 + k2i) * 8 + k3p];
    *(float4*)&xsf[x1 * 18 + 2 * k3p] = v;
  }
  __syncthreads();
  {
    const int k3p = t & 7, slot = (t >> 3) & 15, h = t >> 7;
    const bool isz = (slot == 0);
    const int kk = isz ? 48 : slot;
    float Pa=0,Qa=0,Ra=0,Sa=0, Pb=0,Qb=0,Rb=0,Sb=0, Aa=0,Ba=0,Ab=0,Bb=0;
    int idx = (kk * 16 * h) & 63;
#pragma unroll
    for (int i = 0; i < 16; ++i) {
      int x1 = 16 * h + i;
      float4 v = *(const float4*)&xsf[x1 * 18 + 2 * k3p];
      float2 w = tw[idx]; idx = (idx + kk) & 63;
      Pa = fmaf(v.x, w.x, Pa); Qa = fmaf(v.y, w.y, Qa);
      Ra = fmaf(v.y, w.x, Ra); Sa = fmaf(v.x, w.y, Sa);
      Pb = fmaf(v.z, w.x, Pb); Qb = fmaf(v.w, w.y, Qb);
      Rb = fmaf(v.w, w.x, Rb); Sb = fmaf(v.z, w.y, Sb);
      if (isz) { Aa += v.x; Ba += v.y; Ab += v.z; Bb += v.w; }
    }
    red[0][k3p + 8 * slot + 128 * h] = make_float4(Pa, Qa, Ra, Sa);
    red[1][k3p + 8 * slot + 128 * h] = make_float4(Pb, Qb, Rb, Sb);
    if (isz) redAB[8 * h + k3p] = make_float4(Aa, Ba, Ab, Bb);
  }
  __syncthreads();
  if (t < 256) {
    const int slot = t >> 4, k3 = t & 15, k3p = k3 >> 1, half = k3 & 1;
    int b = k3p + 8 * slot;
    float4 s0 = red[half][b], s1 = red[half][b + 128];
    float4 s2 = red[half][b + 256], s3 = red[half][b + 384];
    float P = s0.x + s1.x + s2.x + s3.x, Q = s0.y + s1.y + s2.y + s3.y;
    float R = s0.z + s1.z + s2.z + s3.z, S = s0.w + s1.w + s2.w + s3.w;
    float2 oa = make_float2(P + Q, R - S);
    float2 ob; int ka, kb;
    if (slot == 0) {
      ka = 16; kb = 0;
      const float2* ab = (const float2*)redAB;
      float2 z0 = ab[(0 * 8 + k3p) * 2 + half], z1 = ab[(1 * 8 + k3p) * 2 + half];
      float2 z2 = ab[(2 * 8 + k3p) * 2 + half], z3 = ab[(3 * 8 + k3p) * 2 + half];
      ob = make_float2(z0.x + z1.x + z2.x + z3.x, z0.y + z1.y + z2.y + z3.y);
    } else {
      ka = slot; kb = 32 - slot;
      ob = make_float2(P - Q, R + S);
    }
    o[(((size_t)bci * 32 + ka) * 32 + k2i) * 16 + k3] = oa;
    o[(((size_t)bci * 32 + kb) * 32 + k2i) * 16 + k3] = ob;
  }
}

// ============================ MIX ============================
__global__ __launch_bounds__(512) void k_mix(const float2* __restrict__ X,
                                             const float2* __restrict__ w0,
                                             const float2* __restrict__ w1,
                                             const float2* __restrict__ w2,
                                             const float2* __restrict__ w3,
                                             float2* __restrict__ Y) {
  __shared__ float2 xs[2048];  // [b*32+ci][k3]
  const int t = threadIdx.x;
  const int k1i = blockIdx.x >> 5, k2i = blockIdx.x & 31;
  const float2* w = (k1i < 16) ? ((k2i < 16) ? w0 : w1) : ((k2i < 16) ? w2 : w3);
  const int a = k1i & 15, bb = k2i & 15;
  for (int q = t; q < 2048; q += 512) {
    int bci = q >> 4, k3 = q & 15;
    xs[q] = X[((size_t)bci * 1024 + blockIdx.x) * 16 + k3];
  }
  __syncthreads();
  const int k3 = t & 15, co = t >> 4;
  float2 a0 = {0,0}, a1 = {0,0}, a2 = {0,0}, a3 = {0,0};
  const float2* wp = w + (size_t)co * 4096 + a * 256 + bb * 16 + k3;
#pragma unroll 4
  for (int ci = 0; ci < 32; ++ci) {
    float2 wv = wp[(size_t)ci * 131072];
    float2 x0 = xs[(0 * 32 + ci) * 16 + k3];
    float2 x1 = xs[(1 * 32 + ci) * 16 + k3];
    float2 x2 = xs[(2 * 32 + ci) * 16 + k3];
    float2 x3 = xs[(3 * 32 + ci) * 16 + k3];
    a0.x = fmaf(x0.x, wv.x, a0.x); a0.x = fmaf(-x0.y, wv.y, a0.x);
    a0.y = fmaf(x0.x, wv.y, a0.y); a0.y = fmaf(x0.y, wv.x, a0.y);
    a1.x = fmaf(x1.x, wv.x, a1.x); a1.x = fmaf(-x1.y, wv.y, a1.x);
    a1.y = fmaf(x1.x, wv.y, a1.y); a1.y = fmaf(x1.y, wv.x, a1.y);
    a2.x = fmaf(x2.x, wv.x, a2.x); a2.x = fmaf(-x2.y, wv.y, a2.x);
    a2.y = fmaf(x2.x, wv.y, a2.y); a2.y = fmaf(x2.y, wv.x, a2.y);
    a3.x = fmaf(x3.x, wv.x, a3.x); a3.x = fmaf(-x3.y, wv.y, a3.x);
    a3.y = fmaf(x3.x, wv.y, a3.y); a3.y = fmaf(x3.y, wv.x, a3.y);
  }
  const float nrm = 1.0f / 262144.0f;  // 1/64^3
  Y[((size_t)(0 * 32 + co) * 1024 + blockIdx.x) * 16 + k3] = make_float2(a0.x * nrm, a0.y * nrm);
  Y[((size_t)(1 * 32 + co) * 1024 + blockIdx.x) * 16 + k3] = make_float2(a1.x * nrm, a1.y * nrm);
  Y[((size_t)(2 * 32 + co) * 1024 + blockIdx.x) * 16 + k3] = make_float2(a2.x * nrm, a2.y * nrm);
  Y[((size_t)(3 * 32 + co) * 1024 + blockIdx.x) * 16 + k3] = make_float2(a3.x * nrm, a3.y * nrm);
}

// ============================ I1 ============================
// per (bco,k2i). 256 thr: k3p = t&7, x1 = t>>3 in [0,32) (pairs with x1+32).
__global__ __launch_bounds__(256) void k_i1(const float2* __restrict__ Y,
                                            float2* __restrict__ o) {
  __shared__ float2 zs[32 * 18];
  __shared__ float2 tw[64];
  const int t = threadIdx.x;
  init_tw2(tw, t);
  const int bco = blockIdx.x >> 5, k2i = blockIdx.x & 31;
  {
    int k1i = t >> 3, k3p = t & 7;
    float4 v = ((const float4*)Y)[((size_t)(bco * 32 + k1i) * 32 + k2i) * 8 + k3p];
    *(float4*)&zs[k1i * 18 + 2 * k3p] = v;
  }
  __syncthreads();
  const int k3p = t & 7, x1 = t >> 3;
  float Er0=0,Ei0=0,Or0=0,Oi0=0, Er1=0,Ei1=0,Or1=0,Oi1=0;
#pragma unroll
  for (int m = 0; m < 16; ++m) {
    int e = 2 * m, od = 2 * m + 1;
    int ke = e + ((e >= 16) ? 32 : 0);
    int ko = od + ((od >= 16) ? 32 : 0);
    float4 ve = *(const float4*)&zs[e * 18 + 2 * k3p];
    float2 we = tw[(ke * x1) & 63];
    Er0 = fmaf(ve.x, we.x, Er0); Er0 = fmaf(-ve.y, we.y, Er0);
    Ei0 = fmaf(ve.y, we.x, Ei0); Ei0 = fmaf(ve.x, we.y, Ei0);
    Er1 = fmaf(ve.z, we.x, Er1); Er1 = fmaf(-ve.w, we.y, Er1);
    Ei1 = fmaf(ve.w, we.x, Ei1); Ei1 = fmaf(ve.z, we.y, Ei1);
    float4 vo = *(const float4*)&zs[od * 18 + 2 * k3p];
    float2 wo = tw[(ko * x1) & 63];
    Or0 = fmaf(vo.x, wo.x, Or0); Or0 = fmaf(-vo.y, wo.y, Or0);
    Oi0 = fmaf(vo.y, wo.x, Oi0); Oi0 = fmaf(vo.x, wo.y, Oi0);
    Or1 = fmaf(vo.z, wo.x, Or1); Or1 = fmaf(-vo.w, wo.y, Or1);
    Oi1 = fmaf(vo.w, wo.x, Oi1); Oi1 = fmaf(vo.z, wo.y, Oi1);
  }
  ((float4*)o)[((size_t)(bco * 64 + x1) * 32 + k2i) * 8 + k3p] =
      make_float4(Er0 + Or0, Ei0 + Oi0, Er1 + Or1, Ei1 + Oi1);
  ((float4*)o)[((size_t)(bco * 64 + x1 + 32) * 32 + k2i) * 8 + k3p] =
      make_float4(Er0 - Or0, Ei0 - Oi0, Er1 - Or1, Ei1 - Oi1);
}

// ============================ I23 ============================
// per (bco,x1). 512 thr. Stage A (t<256): inverse k2->x2, k3-paired.
// Stage B: irfft k3->x3 with 4-way x3 tiling via i^k trick.
__global__ __launch_bounds__(512) void k_i23(const float2* __restrict__ Z1,
                                             float* __restrict__ out) {
  __shared__ float2 zs[32 * 18];  // [k2i][k3] pad-18
  __shared__ float2 Zc[64 * 18];  // [x2][k3] pad-18, Hermitian 2x folded
  __shared__ float2 tw[64];
  const int t = threadIdx.x;
  init_tw2(tw, t);
  if (t < 256) {
    int k2i = t >> 3, k3p = t & 7;
    float4 v = ((const float4*)(Z1 + (size_t)blockIdx.x * 512))[t];
    *(float4*)&zs[k2i * 18 + 2 * k3p] = v;
  }
  __syncthreads();
  if (t < 256) {  // stage A
    const int k3p = t & 7, x2 = t >> 3;  // x2 in [0,32), pairs with x2+32
    float Er0=0,Ei0=0,Or0=0,Oi0=0, Er1=0,Ei1=0,Or1=0,Oi1=0;
#pragma unroll
    for (int m = 0; m < 16; ++m) {
      int e = 2 * m, od = 2 * m + 1;
      int ke = e + ((e >= 16) ? 32 : 0);
      int ko = od + ((od >= 16) ? 32 : 0);
      float4 ve = *(const float4*)&zs[e * 18 + 2 * k3p];
      float2 we = tw[(ke * x2) & 63];
      Er0 = fmaf(ve.x, we.x, Er0); Er0 = fmaf(-ve.y, we.y, Er0);
      Ei0 = fmaf(ve.y, we.x, Ei0); Ei0 = fmaf(ve.x, we.y, Ei0);
      Er1 = fmaf(ve.z, we.x, Er1); Er1 = fmaf(-ve.w, we.y, Er1);
      Ei1 = fmaf(ve.w, we.x, Ei1); Ei1 = fmaf(ve.z, we.y, Ei1);
      float4 vo = *(const float4*)&zs[od * 18 + 2 * k3p];
      float2 wo = tw[(ko * x2) & 63];
      Or0 = fmaf(vo.x, wo.x, Or0); Or0 = fmaf(-vo.y, wo.y, Or0);
      Oi0 = fmaf(vo.y, wo.x, Oi0); Oi0 = fmaf(vo.x, wo.y, Oi0);
      Or1 = fmaf(vo.z, wo.x, Or1); Or1 = fmaf(-vo.w, wo.y, Or1);
      Oi1 = fmaf(vo.w, wo.x, Oi1); Oi1 = fmaf(vo.z, wo.y, Oi1);
    }
    float sc0 = (k3p == 0) ? 1.f : 2.f;  // k3=0 not doubled; k3>0 doubled
    Zc[(x2)*18 + 2*k3p]       = make_float2(sc0 * (Er0 + Or0), sc0 * (Ei0 + Oi0));
    Zc[(x2)*18 + 2*k3p + 1]   = make_float2(2.f * (Er1 + Or1), 2.f * (Ei1 + Oi1));
    Zc[(x2+32)*18 + 2*k3p]     = make_float2(sc0 * (Er0 - Or0), sc0 * (Ei0 - Oi0));
    Zc[(x2+32)*18 + 2*k3p + 1] = make_float2(2.f * (Er1 - Or1), 2.f * (Ei1 - Oi1));
  }
  __syncthreads();
  // stage B: out(x3b+16m) = sum_k Re(z_k w(k*x3b) i^{km})
  {
    const int x3b = t & 15, x2g = t >> 4;  // x2g in [0,32)
    float2 wk[16];
    int idx = 0;
#pragma unroll
    for (int k = 0; k < 16; ++k) { wk[k] = tw[idx]; idx = (idx + x3b) & 63; }
    float* ob = out + (size_t)blockIdx.x * 4096;
#pragma unroll
    for (int rr = 0; rr < 2; ++rr) {
      int x2 = x2g + 32 * rr;
      const float4* zp = (const float4*)&Zc[x2 * 18];
      float Sa0=0, Sa1=0, Sa2=0, Sa3=0, Sb1=0, Sb3=0;
#pragma unroll
      for (int j = 0; j < 8; ++j) {
        float4 z = zp[j];  // cplx 2j (x,y) and 2j+1 (z,w)
        float2 we = wk[2 * j], wo = wk[2 * j + 1];
        if ((j & 1) == 0) {  // k=2j ≡ 0 (mod 4), k=2j+1 ≡ 1
          Sa0 = fmaf(z.x, we.x, Sa0); Sa0 = fmaf(-z.y, we.y, Sa0);
          Sa1 = fmaf(z.z, wo.x, Sa1); Sa1 = fmaf(-z.w, wo.y, Sa1);
          Sb1 = fmaf(z.z, wo.y, Sb1); Sb1 = fmaf(z.w, wo.x, Sb1);
        } else {             // k=2j ≡ 2, k=2j+1 ≡ 3
          Sa2 = fmaf(z.x, we.x, Sa2); Sa2 = fmaf(-z.y, we.y, Sa2);
          Sa3 = fmaf(z.z, wo.x, Sa3); Sa3 = fmaf(-z.w, wo.y, Sa3);
          Sb3 = fmaf(z.z, wo.y, Sb3); Sb3 = fmaf(z.w, wo.x, Sb3);
        }
      }
      ob[x2 * 64 + x3b]      = Sa0 + Sa1 + Sa2 + Sa3;
      ob[x2 * 64 + x3b + 16] = Sa0 - Sb1 - Sa2 + Sb3;
      ob[x2 * 64 + x3b + 32] = Sa0 - Sa1 + Sa2 - Sa3;
      ob[x2 * 64 + x3b + 48] = Sa0 + Sb1 - Sa2 - Sb3;
    }
  }
}

extern "C" void kernel_launch(void* const* d_in, const int* in_sizes, int n_in,
                              void* d_out, int out_size, void* d_ws, size_t ws_size,
                              hipStream_t stream) {
  (void)in_sizes; (void)n_in; (void)out_size; (void)ws_size;
  const float* x = (const float*)d_in[0];
  const float2* w0 = (const float2*)d_in[1];
  const float2* w1 = (const float2*)d_in[2];
  const float2* w2 = (const float2*)d_in[3];
  const float2* w3 = (const float2*)d_in[4];
  float* out = (float*)d_out;
  char* ws = (char*)d_ws;

  // Workspace (67,108,864 B):
  //  B1 = ws[0 : 33.5MB)    f23 out; dead after f1 -> reused as B2 (i1 out)
  //  C  = ws[33.5 : 50.3MB) f1 out
  //  D  = ws[50.3 : 67.1MB) mix out
  float2* B1 = (float2*)ws;
  float2* C  = (float2*)(ws + 33554432);
  float2* D  = (float2*)(ws + 50331648);
  float2* B2 = B1;

  k_f23<<<8192, 512, 0, stream>>>(x, B1);
  k_f1 <<<4096, 512, 0, stream>>>(B1, C);
  k_mix<<<1024, 512, 0, stream>>>(C, w0, w1, w2, w3, D);
  k_i1 <<<4096, 256, 0, stream>>>(D, B2);
  k_i23<<<8192, 512, 0, stream>>>(B2, out);
}